// Round 11
// baseline (112.886 us; speedup 1.0000x reference)
//
#include <hip/hip_runtime.h>

typedef __attribute__((ext_vector_type(8))) short short8;
typedef __attribute__((ext_vector_type(16))) float f32x16;

#define MFMA32 __builtin_amdgcn_mfma_f32_32x32x16_bf16

__device__ __forceinline__ unsigned short f2bf(float f) {
  unsigned int u = __float_as_uint(f);
  u += 0x7fffu + ((u >> 16) & 1u);
  return (unsigned short)(u >> 16);
}

__device__ __forceinline__ float bf2f(unsigned short s) {
  unsigned int u = ((unsigned int)s) << 16;
  return __uint_as_float(u);
}

// Pre-pack the 6 weight matrices fp32 [k][n] -> bf16 MFMA-fragment order:
// wt[(((s*6 + g)*8 + c)*64 + l)*8 + j] = G_g[k][n]
//   with k = s*16 + (l>>5)*8 + j, n = c*32 + (l&31)
// One (slab,gate,chunk) brick = 1 KB = one wave's B-fragment, contiguous.
__global__ __launch_bounds__(256) void wprep(
    const float* __restrict__ Wu, const float* __restrict__ Wr, const float* __restrict__ Wh,
    const float* __restrict__ Uu, const float* __restrict__ Ur, const float* __restrict__ Uh,
    unsigned short* __restrict__ wt) {
  int idx = blockIdx.x * 256 + threadIdx.x;   // 0 .. 6*65536-1
  int j = idx & 7;
  int l = (idx >> 3) & 63;
  int c = (idx >> 9) & 7;
  int sg = idx >> 12;
  int g = sg % 6;
  int s = sg / 6;
  int k = s * 16 + (l >> 5) * 8 + j;
  int n = c * 32 + (l & 31);
  const float* src = (g == 0) ? Wu : (g == 1) ? Wr : (g == 2) ? Wh
                   : (g == 3) ? Uu : (g == 4) ? Ur : Uh;
  wt[idx] = f2bf(src[k * 256 + n]);
}

// Fused AUGRU. Block = 512 thr (8 waves), tile 64 rows x 256 cols.
// Wave w owns cols [32w,32w+32), all 64 rows, mfma 32x32x16, acc 8 x f32x16.
// x/h LDS layout: brick[slab16][frag2] of 64 slots x 16B, slot XOR-swizzled:
//   element (r,k): slab=k>>4, frag=r>>5, slot=(r&31)|(((k>>3)&1)<<5),
//   addr = slab*2048 + frag*1024 + ((slot^(slab&7))<<4) + (k&7)*2.
// -> staging writes, K-loop b128 reads, and epilogue u16 gathers all <=2-way.
// Weights: global->VGPR ring depth 4. No barriers inside K-loops.
__global__ __launch_bounds__(512, 2) void augru_main(
    const float* __restrict__ x, const float* __restrict__ h1,
    const float* __restrict__ a, const unsigned short* __restrict__ wt,
    const float* __restrict__ bu, const float* __restrict__ br,
    const float* __restrict__ bh, float* __restrict__ out) {
  __shared__ char lX[32768];
  __shared__ char lH[32768];
  __shared__ float a_s[64];

  const int tid = threadIdx.x;
  const int l   = tid & 63;
  const int wid = tid >> 6;            // 0..7 -> 32-col chunk
  const int fq  = l >> 5;
  const long rowbase = (long)blockIdx.x * 64;
  const int n = wid * 32 + (l & 31);
  const char* wb = (const char*)wt + (wid << 10) + (l << 4);
#define WOFF(SG) ((long)(SG) << 13)

  const float* xsrc = x + rowbase * 256;
  const float* hsrc = h1 + rowbase * 256;

  // ---- issue x tile loads ----
  float4 xv[8];
#pragma unroll
  for (int i = 0; i < 8; ++i) xv[i] = ((const float4*)xsrc)[i * 512 + tid];

  // ---- W ring init: slabs 0..3, x-gates ----
  short8 W[4][3];
#pragma unroll
  for (int i = 0; i < 4; ++i) {
#pragma unroll
    for (int g = 0; g < 3; ++g)
      W[i][g] = *(const short8*)(wb + WOFF(i * 6 + g));
  }

  // ---- issue first half of h tile loads ----
  float4 hv[8];
#pragma unroll
  for (int i = 0; i < 4; ++i) hv[i] = ((const float4*)hsrc)[i * 512 + tid];

  const float vbu = bu[n], vbr = br[n], vbh = bh[n];
  if (tid < 64) a_s[tid] = a[rowbase + tid];

  // ---- tile write: thread's float4 i covers (row r, k-quad kq) ----
#define TWRITE(DST, V, I)                                                   \
  {                                                                         \
    const int f_ = (I) * 512 + tid;                                         \
    const int r_ = f_ >> 6;                                                 \
    const int kq_ = f_ & 63;              /* k0 = kq*4 */                   \
    const int slab_ = kq_ >> 2;                                             \
    const int slot_ = (r_ & 31) | (((kq_ >> 1) & 1) << 5);                  \
    const int addr_ = (slab_ << 11) + ((r_ >> 5) << 10)                     \
        + (((slot_ ^ (slab_ & 7))) << 4) + ((kq_ & 1) << 3);                \
    ushort4 b_;                                                             \
    b_.x = f2bf((V).x); b_.y = f2bf((V).y);                                 \
    b_.z = f2bf((V).z); b_.w = f2bf((V).w);                                 \
    *(ushort4*)((DST) + addr_) = b_;                                        \
  }

#pragma unroll
  for (int i = 0; i < 8; ++i) TWRITE(lX, xv[i], i)
  __syncthreads();   // lX ready

  f32x16 accU0 = {}, accU1 = {}, accR0 = {}, accR1 = {};
  f32x16 accXH0 = {}, accXH1 = {}, accHH0 = {}, accHH1 = {};

  // A-fragment read: slab s, frag m, lane l at s*2048+m*1024+((l^(s&7))<<4)
#define ARD(SRC, S, M) \
  (*(const short8*)((SRC) + ((S) << 11) + ((M) << 10) + (((l ^ ((S) & 7))) << 4)))

  short8 aF[2][2];
  aF[0][0] = ARD(lX, 0, 0);
  aF[0][1] = ARD(lX, 0, 1);

  // ---- x-pass: slabs 0..15, gates 0-2 (Wu,Wr,Wh). No barriers. ----
#pragma unroll
  for (int p = 0; p < 16; ++p) {
    if (p < 15) {   // A prefetch next slab
      aF[(p + 1) & 1][0] = ARD(lX, p + 1, 0);
      aF[(p + 1) & 1][1] = ARD(lX, p + 1, 1);
    }
    const short8 a0 = aF[p & 1][0];
    const short8 a1 = aF[p & 1][1];
    accU0  = MFMA32(a0, W[p & 3][0], accU0, 0, 0, 0);
    accU1  = MFMA32(a1, W[p & 3][0], accU1, 0, 0, 0);
    accR0  = MFMA32(a0, W[p & 3][1], accR0, 0, 0, 0);
    accR1  = MFMA32(a1, W[p & 3][1], accR1, 0, 0, 0);
    accXH0 = MFMA32(a0, W[p & 3][2], accXH0, 0, 0, 0);
    accXH1 = MFMA32(a1, W[p & 3][2], accXH1, 0, 0, 0);
    // W ring refill for position p+4; rolls into h-gate slabs 0..3
    {
      const long ro = (p + 4 < 16) ? WOFF((p + 4) * 6) : WOFF((p - 12) * 6 + 3);
      W[p & 3][0] = *(const short8*)(wb + ro);
      W[p & 3][1] = *(const short8*)(wb + ro + 8192);
      W[p & 3][2] = *(const short8*)(wb + ro + 16384);
    }
    if (p == 4) {
#pragma unroll
      for (int i = 4; i < 8; ++i) hv[i] = ((const float4*)hsrc)[i * 512 + tid];
    }
    if (p == 8) {
      TWRITE(lH, hv[0], 0) TWRITE(lH, hv[1], 1)
      TWRITE(lH, hv[2], 2) TWRITE(lH, hv[3], 3)
    }
    if (p == 12) {
      TWRITE(lH, hv[4], 4) TWRITE(lH, hv[5], 5)
      TWRITE(lH, hv[6], 6) TWRITE(lH, hv[7], 7)
    }
  }
  __syncthreads();   // lH ready

  aF[0][0] = ARD(lH, 0, 0);
  aF[0][1] = ARD(lH, 0, 1);

  // ---- h-pass: slabs 0..15, gates 3-5 (Uu,Ur,Uh). No barriers. ----
#pragma unroll
  for (int p = 0; p < 16; ++p) {
    if (p < 15) {
      aF[(p + 1) & 1][0] = ARD(lH, p + 1, 0);
      aF[(p + 1) & 1][1] = ARD(lH, p + 1, 1);
    }
    const short8 a0 = aF[p & 1][0];
    const short8 a1 = aF[p & 1][1];
    accU0  = MFMA32(a0, W[p & 3][0], accU0, 0, 0, 0);
    accU1  = MFMA32(a1, W[p & 3][0], accU1, 0, 0, 0);
    accR0  = MFMA32(a0, W[p & 3][1], accR0, 0, 0, 0);
    accR1  = MFMA32(a1, W[p & 3][1], accR1, 0, 0, 0);
    accHH0 = MFMA32(a0, W[p & 3][2], accHH0, 0, 0, 0);
    accHH1 = MFMA32(a1, W[p & 3][2], accHH1, 0, 0, 0);
    if (p + 4 < 16) {
      const long ro = WOFF((p + 4) * 6 + 3);
      W[p & 3][0] = *(const short8*)(wb + ro);
      W[p & 3][1] = *(const short8*)(wb + ro + 8192);
      W[p & 3][2] = *(const short8*)(wb + ro + 16384);
    }
  }

  // ---- epilogue: h1 from LDS (brick layout, ~conflict-free), gates, blend ----
  // h1[rl][n]: slab=n>>4, frag=rl>>5, slot=(rl&31)|(((n>>3)&1)<<5), byte=(n&7)*2
#define HLD(RL)                                                             \
  bf2f(*(const unsigned short*)(lH + ((n >> 4) << 11) + (((RL) >> 5) << 10) \
      + (((((RL) & 31) | (((n >> 3) & 1) << 5)) ^ ((n >> 4) & 7)) << 4)     \
      + ((n & 7) << 1)))

  float* ocol = out + rowbase * 256 + n;

#define EPI(ACCU, ACCR, ACCXH, ACCHH, RB)                                   \
  _Pragma("unroll")                                                         \
  for (int g8 = 0; g8 < 4; ++g8) {                                          \
    _Pragma("unroll")                                                       \
    for (int j = 0; j < 4; ++j) {                                           \
      const int reg = g8 * 4 + j;                                           \
      const int rl  = (RB) + g8 * 8 + fq * 4 + j;                           \
      const float pu = ACCU[reg] + vbu;                                     \
      const float pr = ACCR[reg] + vbr;                                     \
      const float uu = __builtin_amdgcn_rcpf(1.f + __expf(-pu));            \
      const float rr = __builtin_amdgcn_rcpf(1.f + __expf(-pr));            \
      const float cc = fmaf(rr, ACCHH[reg], ACCXH[reg]) + vbh;              \
      const float tt = __builtin_amdgcn_rcpf(1.f + __expf(-2.f * cc));      \
      const float th = fmaf(2.f, tt, -1.f);                                 \
      const float uh = a_s[rl] * uu;                                        \
      const float h1v = HLD(rl);                                            \
      ocol[(long)rl * 256] = fmaf(uh, th - h1v, h1v);                       \
    }                                                                       \
  }

  EPI(accU0, accR0, accXH0, accHH0, 0)
  EPI(accU1, accR1, accXH1, accHH1, 32)
#undef EPI
#undef HLD
#undef ARD
#undef TWRITE
#undef WOFF
}

extern "C" void kernel_launch(void* const* d_in, const int* in_sizes, int n_in,
                              void* d_out, int out_size, void* d_ws, size_t ws_size,
                              hipStream_t stream) {
  const float* x  = (const float*)d_in[0];
  const float* h1 = (const float*)d_in[1];
  const float* a  = (const float*)d_in[2];
  const float* Wu = (const float*)d_in[3];
  const float* Uu = (const float*)d_in[4];
  const float* bu = (const float*)d_in[5];
  const float* Wr = (const float*)d_in[6];
  const float* Ur = (const float*)d_in[7];
  const float* br = (const float*)d_in[8];
  const float* Wh = (const float*)d_in[9];
  const float* Uh = (const float*)d_in[10];
  const float* bh = (const float*)d_in[11];
  unsigned short* wt = (unsigned short*)d_ws;   // 16 slabs x 48 KB = 768 KB

  wprep<<<1536, 256, 0, stream>>>(Wu, Wr, Wh, Uu, Ur, Uh, wt);

  const int rows = in_sizes[0] / 256;           // 65536
  augru_main<<<rows / 64, 512, 0, stream>>>(x, h1, a, wt, bu, br, bh,
                                            (float*)d_out);
}

// Round 12
// 108.001 us; speedup vs baseline: 1.0452x; 1.0452x over previous
//
#include <hip/hip_runtime.h>

typedef __attribute__((ext_vector_type(8))) short short8;
typedef __attribute__((ext_vector_type(16))) float f32x16;

#define MFMA32 __builtin_amdgcn_mfma_f32_32x32x16_bf16

__device__ __forceinline__ unsigned short f2bf(float f) {
  unsigned int u = __float_as_uint(f);
  u += 0x7fffu + ((u >> 16) & 1u);
  return (unsigned short)(u >> 16);
}

// Pre-pack the 6 weight matrices fp32 [k][n] -> bf16 MFMA-fragment order:
// wt[(((s*6 + g)*8 + c)*64 + l)*8 + j] = G_g[k][n]
//   with k = s*16 + (l>>5)*8 + j, n = c*32 + (l&31)
// One (slab,gate,chunk) brick = 1 KB = one wave's B-fragment, contiguous.
__global__ __launch_bounds__(256) void wprep(
    const float* __restrict__ Wu, const float* __restrict__ Wr, const float* __restrict__ Wh,
    const float* __restrict__ Uu, const float* __restrict__ Ur, const float* __restrict__ Uh,
    unsigned short* __restrict__ wt) {
  int idx = blockIdx.x * 256 + threadIdx.x;   // 0 .. 6*65536-1
  int j = idx & 7;
  int l = (idx >> 3) & 63;
  int c = (idx >> 9) & 7;
  int sg = idx >> 12;
  int g = sg % 6;
  int s = sg / 6;
  int k = s * 16 + (l >> 5) * 8 + j;
  int n = c * 32 + (l & 31);
  const float* src = (g == 0) ? Wu : (g == 1) ? Wr : (g == 2) ? Wh
                   : (g == 3) ? Uu : (g == 4) ? Ur : Uh;
  wt[idx] = f2bf(src[k * 256 + n]);
}

// Fused AUGRU. Block = 512 thr (8 waves), tile 128 rows x 128 cols
// (bid&1 = col half, bid>>1 = row stripe). Wave (wrow=wid>>2, wc=wid&3):
// rows wrow*64..+64, cols chunk=(bid&1)*4+wc. Same wave tile/acc/ring as the
// 92us BM=64 kernel, but block reads HALF the weights -> per-CU weight-L2
// bytes per slab drop 24->12 KB (below the 384-cyc MFMA pipe time).
// Weights: global->VGPR ring depth 4, no barriers in K-loops.
__global__ __launch_bounds__(512, 2) void augru_main(
    const float* __restrict__ x, const float* __restrict__ h1,
    const float* __restrict__ a, const unsigned short* __restrict__ wt,
    const float* __restrict__ bu, const float* __restrict__ br,
    const float* __restrict__ bh, float* __restrict__ out) {
  extern __shared__ char smem[];
  char* lX = smem;                       // 65536 B x tile (128 rows)
  char* lH = smem + 65536;               // 65536 B h tile (128 rows)
  float* a_s = (float*)(smem + 131072);  // 128 floats

  const int tid  = threadIdx.x;
  const int l    = tid & 63;
  const int wid  = tid >> 6;           // 0..7
  const int wrow = wid >> 2;           // 0..1 -> row group
  const int wc   = wid & 3;            // 0..3 -> col chunk within half
  const int fr   = l & 31;
  const int fq   = l >> 5;
  const int bid  = blockIdx.x;
  const long rowbase = (long)(bid >> 1) * 128;
  const int chunk = (bid & 1) * 4 + wc;          // 0..7
  const int n = (chunk << 5) + fr;
  const int aswz = (fr & 7) << 4;
  const int arow = (wrow << 6) + fr;             // wave A row (+0/+32)

  const char* wb = (const char*)wt + (chunk << 10) + (l << 4);
#define WOFF(SG) ((long)(SG) << 13)

  const float* xsrc = x + rowbase * 256;
  const float* hsrc = h1 + rowbase * 256;

  // ---- issue x tile loads (128 rows = 16 float4/thread) ----
  float4 xv[16];
#pragma unroll
  for (int i = 0; i < 16; ++i) xv[i] = ((const float4*)xsrc)[i * 512 + tid];

  // ---- W ring init: slabs 0..3, x-gates ----
  short8 W[4][3];
#pragma unroll
  for (int i = 0; i < 4; ++i)
#pragma unroll
    for (int g = 0; g < 3; ++g)
      W[i][g] = *(const short8*)(wb + WOFF(i * 6 + g));

  // ---- issue h rows 0..63 ----
  float4 hv[8];
#pragma unroll
  for (int i = 0; i < 8; ++i) hv[i] = ((const float4*)hsrc)[i * 512 + tid];

  const float vbu = bu[n], vbr = br[n], vbh = bh[n];
  if (tid < 128) a_s[tid] = a[rowbase + tid];

  // ---- tile write (row-XOR swizzle, proven in the 92us kernel) ----
#define TWRITE(DST, V, I)                                                   \
  {                                                                         \
    const int f_ = (I) * 512 + tid;                                         \
    const int row_ = f_ >> 6;                                               \
    const int kq_ = f_ & 63;                                                \
    ushort4 b_;                                                             \
    b_.x = f2bf((V).x); b_.y = f2bf((V).y);                                 \
    b_.z = f2bf((V).z); b_.w = f2bf((V).w);                                 \
    *(ushort4*)((DST) + (row_ << 9) + ((kq_ * 8) ^ ((row_ & 7) << 4))) = b_;\
  }

#pragma unroll
  for (int i = 0; i < 16; ++i) TWRITE(lX, xv[i], i)
  __syncthreads();   // lX ready

  f32x16 accU0 = {}, accU1 = {}, accR0 = {}, accR1 = {};
  f32x16 accXH0 = {}, accXH1 = {}, accHH0 = {}, accHH1 = {};

  // ---- x-pass: slabs 0..15, gates 0-2 (Wu,Wr,Wh). No barriers. ----
#pragma unroll
  for (int p = 0; p < 16; ++p) {
    const int koff = ((p << 5) + (fq << 4)) ^ aswz;
    short8 ax0 = *(const short8*)(lX + (arow << 9) + koff);
    short8 ax1 = *(const short8*)(lX + ((arow + 32) << 9) + koff);
    accU0  = MFMA32(ax0, W[p & 3][0], accU0, 0, 0, 0);
    accU1  = MFMA32(ax1, W[p & 3][0], accU1, 0, 0, 0);
    accR0  = MFMA32(ax0, W[p & 3][1], accR0, 0, 0, 0);
    accR1  = MFMA32(ax1, W[p & 3][1], accR1, 0, 0, 0);
    accXH0 = MFMA32(ax0, W[p & 3][2], accXH0, 0, 0, 0);
    accXH1 = MFMA32(ax1, W[p & 3][2], accXH1, 0, 0, 0);
    // ring refill for slab p+4; rolls into h-gate slabs 0..3
    {
      const long ro = (p + 4 < 16) ? WOFF((p + 4) * 6) : WOFF((p - 12) * 6 + 3);
      W[p & 3][0] = *(const short8*)(wb + ro);
      W[p & 3][1] = *(const short8*)(wb + ro + 8192);
      W[p & 3][2] = *(const short8*)(wb + ro + 16384);
    }
    if (p == 6) {   // write h rows 0..63; issue h rows 64..127
      TWRITE(lH, hv[0], 0) TWRITE(lH, hv[1], 1)
      TWRITE(lH, hv[2], 2) TWRITE(lH, hv[3], 3)
      TWRITE(lH, hv[4], 4) TWRITE(lH, hv[5], 5)
      TWRITE(lH, hv[6], 6) TWRITE(lH, hv[7], 7)
#pragma unroll
      for (int i = 0; i < 8; ++i)
        hv[i] = ((const float4*)hsrc)[(i + 8) * 512 + tid];
    }
    if (p == 13) {  // write h rows 64..127
      TWRITE(lH, hv[0], 8)  TWRITE(lH, hv[1], 9)
      TWRITE(lH, hv[2], 10) TWRITE(lH, hv[3], 11)
      TWRITE(lH, hv[4], 12) TWRITE(lH, hv[5], 13)
      TWRITE(lH, hv[6], 14) TWRITE(lH, hv[7], 15)
    }
  }
  __syncthreads();   // lH ready

  // ---- h-pass: slabs 0..15, gates 3-5 (Uu,Ur,Uh). No barriers. ----
#pragma unroll
  for (int p = 0; p < 16; ++p) {
    const int koff = ((p << 5) + (fq << 4)) ^ aswz;
    short8 ah0 = *(const short8*)(lH + (arow << 9) + koff);
    short8 ah1 = *(const short8*)(lH + ((arow + 32) << 9) + koff);
    accU0  = MFMA32(ah0, W[p & 3][0], accU0, 0, 0, 0);
    accU1  = MFMA32(ah1, W[p & 3][0], accU1, 0, 0, 0);
    accR0  = MFMA32(ah0, W[p & 3][1], accR0, 0, 0, 0);
    accR1  = MFMA32(ah1, W[p & 3][1], accR1, 0, 0, 0);
    accHH0 = MFMA32(ah0, W[p & 3][2], accHH0, 0, 0, 0);
    accHH1 = MFMA32(ah1, W[p & 3][2], accHH1, 0, 0, 0);
    if (p + 4 < 16) {
      const long ro = WOFF((p + 4) * 6 + 3);
      W[p & 3][0] = *(const short8*)(wb + ro);
      W[p & 3][1] = *(const short8*)(wb + ro + 8192);
      W[p & 3][2] = *(const short8*)(wb + ro + 16384);
    }
  }

  // ---- epilogue: coalesced fp32 h1 re-read (L2/L3-hot), gates, blend ----
  const long wrbase = rowbase + (wrow << 6);
  const float* hcol = h1 + wrbase * 256 + n;
  float* ocol = out + wrbase * 256 + n;
  float hE0[16], hE1[16];
#pragma unroll
  for (int g8 = 0; g8 < 4; ++g8)
#pragma unroll
    for (int j = 0; j < 4; ++j) {
      const int rl = g8 * 8 + fq * 4 + j;
      hE0[g8 * 4 + j] = hcol[(long)rl * 256];
      hE1[g8 * 4 + j] = hcol[(long)(rl + 32) * 256];
    }

#define EPI(ACCU, ACCR, ACCXH, ACCHH, HE, RB)                               \
  _Pragma("unroll")                                                         \
  for (int g8 = 0; g8 < 4; ++g8) {                                          \
    _Pragma("unroll")                                                       \
    for (int j = 0; j < 4; ++j) {                                           \
      const int reg = g8 * 4 + j;                                           \
      const int rl  = (RB) + g8 * 8 + fq * 4 + j;                           \
      const float pu = ACCU[reg] + vbu;                                     \
      const float pr = ACCR[reg] + vbr;                                     \
      const float uu = __builtin_amdgcn_rcpf(1.f + __expf(-pu));            \
      const float rr = __builtin_amdgcn_rcpf(1.f + __expf(-pr));            \
      const float cc = fmaf(rr, ACCHH[reg], ACCXH[reg]) + vbh;              \
      const float tt = __builtin_amdgcn_rcpf(1.f + __expf(-2.f * cc));      \
      const float th = fmaf(2.f, tt, -1.f);                                 \
      const float uh = a_s[(wrow << 6) + rl] * uu;                          \
      const float h1v = HE[reg];                                            \
      ocol[(long)rl * 256] = fmaf(uh, th - h1v, h1v);                       \
    }                                                                       \
  }

  EPI(accU0, accR0, accXH0, accHH0, hE0, 0)
  EPI(accU1, accR1, accXH1, accHH1, hE1, 32)
#undef EPI
#undef TWRITE
#undef WOFF
}

extern "C" void kernel_launch(void* const* d_in, const int* in_sizes, int n_in,
                              void* d_out, int out_size, void* d_ws, size_t ws_size,
                              hipStream_t stream) {
  const float* x  = (const float*)d_in[0];
  const float* h1 = (const float*)d_in[1];
  const float* a  = (const float*)d_in[2];
  const float* Wu = (const float*)d_in[3];
  const float* Uu = (const float*)d_in[4];
  const float* bu = (const float*)d_in[5];
  const float* Wr = (const float*)d_in[6];
  const float* Ur = (const float*)d_in[7];
  const float* br = (const float*)d_in[8];
  const float* Wh = (const float*)d_in[9];
  const float* Uh = (const float*)d_in[10];
  const float* bh = (const float*)d_in[11];
  unsigned short* wt = (unsigned short*)d_ws;   // 16 slabs x 48 KB = 768 KB

  wprep<<<1536, 256, 0, stream>>>(Wu, Wr, Wh, Uu, Ur, Uh, wt);

  const int lds_bytes = 131072 + 512;
  hipFuncSetAttribute((const void*)augru_main,
                      hipFuncAttributeMaxDynamicSharedMemorySize, lds_bytes);

  const int rows = in_sizes[0] / 256;           // 65536
  augru_main<<<(rows / 128) * 2, 512, lds_bytes, stream>>>(
      x, h1, a, wt, bu, br, bh, (float*)d_out);
}